// Round 1
// baseline (231.691 us; speedup 1.0000x reference)
//
#include <hip/hip_runtime.h>

#define EPSN 1e-12f

// ---- problem constants ----
#define NB   4
#define CC   128
#define KK_  64
#define HH   40
#define WW   40
#define HWP  1600      // H*W
#define HO   18
#define WO   18
#define HWO  324       // HO*WO
#define KCC  8192      // K*C

// ws layout (floats)
#define WS_XN  0                      // 4*1600*128 = 819200
#define WS_A   819200                 // 4*1600*64  = 409600
#define WS_GP  1228800                // 256*8192   = 2097152
#define WS_G0  3325952                // 256*64     = 16384

// column swizzle for xs tiles: spread the 4 c-phases (stride-32) across banks,
// preserving 4-float contiguity so b128 reads still work.
static __device__ __forceinline__ int swz(int c){ return c ^ ((c & 96) >> 3); }

// =====================================================================
// Kernel 1: per-pixel L2 norm -> xn (pix-major), conv dots + softmax -> a
// grid 100 x 512 threads. 64 pixels per block.
// =====================================================================
__global__ __launch_bounds__(512) void k1_norm_assign(
    const float* __restrict__ x, const float* __restrict__ w,
    float* __restrict__ xn, float* __restrict__ aout)
{
  __shared__ float xs[64][133];   // pad 133: conflict-free for both row- and col-access
  __shared__ float ds[64][65];
  const int t = threadIdx.x;
  const int b = blockIdx.x;          // 0..99
  const int n = b / 25;
  const int pixb = (b % 25) * 64;    // pixel base within image n
  const float* xb = x + (size_t)n * CC * HWP + pixb;

  // ---- Phase A: sumsq + normalize. thread = (p = t>>3, q = t&7), c = q + 8j
  {
    const int p = t >> 3, q = t & 7;
    float vv[16]; float ss = 0.f;
    #pragma unroll
    for (int j = 0; j < 16; ++j){
      float v = xb[(q + 8*j) * HWP + p];
      vv[j] = v; ss += v * v;
    }
    ss += __shfl_xor(ss, 1); ss += __shfl_xor(ss, 2); ss += __shfl_xor(ss, 4);
    const float inv = 1.f / fmaxf(sqrtf(ss), EPSN);
    #pragma unroll
    for (int j = 0; j < 16; ++j) xs[p][q + 8*j] = vv[j] * inv;
  }
  __syncthreads();

  // cooperative coalesced write of xn, layout (n*1600+pix)*128 + c
  {
    float* xno = xn + ((size_t)n * HWP + pixb) * CC;
    for (int i = t; i < 64 * CC; i += 512) {
      int pp = i >> 7, c = i & 127;
      xno[i] = xs[pp][c];
    }
  }

  // ---- Phase B: dots. wave wv handles k = wv*8 .. wv*8+7; lane = pixel.
  // w index is wave-uniform -> scalar loads (no per-lane VMEM for weights).
  {
    const int lane = t & 63;
    const int wv = __builtin_amdgcn_readfirstlane(t >> 6);
    float acc[8];
    #pragma unroll
    for (int kk = 0; kk < 8; ++kk) acc[kk] = 0.f;
    for (int c = 0; c < CC; ++c) {
      float vn = xs[lane][c];
      #pragma unroll
      for (int kk = 0; kk < 8; ++kk)
        acc[kk] += vn * w[(wv * 8 + kk) * CC + c];
    }
    #pragma unroll
    for (int kk = 0; kk < 8; ++kk) ds[lane][wv * 8 + kk] = acc[kk];
  }
  __syncthreads();

  // ---- Phase C: softmax per pixel. thread = (p, q), k = q*8..q*8+7
  {
    const int p = t >> 3, q = t & 7;
    float v[8]; float m = -3.4e38f;
    #pragma unroll
    for (int kk = 0; kk < 8; ++kk){ v[kk] = ds[p][q * 8 + kk]; m = fmaxf(m, v[kk]); }
    m = fmaxf(m, __shfl_xor(m, 1)); m = fmaxf(m, __shfl_xor(m, 2)); m = fmaxf(m, __shfl_xor(m, 4));
    float s = 0.f;
    #pragma unroll
    for (int kk = 0; kk < 8; ++kk){ v[kk] = __expf(v[kk] - m); s += v[kk]; }
    s += __shfl_xor(s, 1); s += __shfl_xor(s, 2); s += __shfl_xor(s, 4);
    const float is = 1.f / s;
    #pragma unroll
    for (int kk = 0; kk < 8; ++kk) ds[p][q * 8 + kk] = v[kk] * is;
  }
  __syncthreads();
  {
    float* ao = aout + ((size_t)n * HWP + pixb) * KK_;
    for (int i = t; i < 64 * KK_; i += 512) {
      int pp = i >> 6, k = i & 63;
      ao[i] = ds[pp][k];
    }
  }
}

// =====================================================================
// shared rank-25 outer-product accumulate: acc[kk][c] += a[k]*xn[c]
// thread = (kq = lane>>2 -> 4 k's, cg = lane&3 -> 32 c's)
// =====================================================================
__device__ __forceinline__ void dots25(const float (*a_s)[64], const float (*xs)[128],
                                       int kq, int cg, float acc[4][32])
{
  #pragma unroll 5
  for (int p = 0; p < 25; ++p) {
    const float4 av4 = *(const float4*)&a_s[p][kq << 2];
    const float av[4] = {av4.x, av4.y, av4.z, av4.w};
    #pragma unroll
    for (int m = 0; m < 8; ++m) {
      const float4 x4 = *(const float4*)&xs[p][(cg << 5) + ((m ^ cg) << 2)];
      const float xv[4] = {x4.x, x4.y, x4.z, x4.w};
      #pragma unroll
      for (int kk = 0; kk < 4; ++kk)
        #pragma unroll
        for (int d = 0; d < 4; ++d)
          acc[kk][(m << 2) + d] += av[kk] * xv[d];
    }
  }
}

// =====================================================================
// Kernel 2: 1296 regional-window blocks (write final vlad) + 256 blocks
// of vlad_full partial sums. 64 threads (1 wave) per block.
// =====================================================================
__global__ __launch_bounds__(64) void k2_main(
    const float* __restrict__ xn, const float* __restrict__ aw,
    const float* __restrict__ cent, float* __restrict__ out,
    float* __restrict__ Gpart, float* __restrict__ G0part)
{
  __shared__ __align__(16) float a_s[25][64];
  __shared__ __align__(16) float xs[25][128];
  __shared__ float s0_s[64];
  const int lane = threadIdx.x;
  const int kq = lane >> 2, cg = lane & 3;
  // XCD-chunked swizzle (1552 % 8 == 0 -> simple bijective form): keeps
  // hw-adjacent blocks on one XCD so scattered 4B output stores merge in L2.
  const int bid = (blockIdx.x & 7) * (1552 >> 3) + (blockIdx.x >> 3);

  float acc[4][32];
  #pragma unroll
  for (int kk = 0; kk < 4; ++kk)
    #pragma unroll
    for (int j = 0; j < 32; ++j) acc[kk][j] = 0.f;

  if (bid < 1296) {
    // ---------------- regional window ----------------
    const int n = bid / HWO, r = bid % HWO, ho = r / WO, wo = r % WO;
    #pragma unroll
    for (int it = 0; it < 25; ++it) {
      const int pix = (2 * ho + it / 5) * WW + 2 * wo + (it % 5);
      a_s[it][lane] = aw[((size_t)n * HWP + pix) * KK_ + lane];
      const float* xp = xn + ((size_t)n * HWP + pix) * CC;
      xs[it][swz(lane)]      = xp[lane];
      xs[it][swz(lane + 64)] = xp[lane + 64];
    }
    __syncthreads();
    float s0 = 0.f;
    #pragma unroll
    for (int p = 0; p < 25; ++p) s0 += a_s[p][lane];
    s0_s[lane] = s0;
    __syncthreads();

    dots25(a_s, xs, kq, cg, acc);

    // epilogue: centroid correction, /25, intra-norm (C), global norm (K*C)
    float rn[4]; float gpart = 0.f;
    float s0k[4];
    #pragma unroll
    for (int kk = 0; kk < 4; ++kk) s0k[kk] = s0_s[(kq << 2) + kk];
    #pragma unroll
    for (int kk = 0; kk < 4; ++kk) {
      const int k = (kq << 2) + kk;
      float ss = 0.f;
      #pragma unroll
      for (int m = 0; m < 8; ++m) {
        const float4 c4 = *(const float4*)&cent[(size_t)k * CC + (cg << 5) + (m << 2)];
        const float cv[4] = {c4.x, c4.y, c4.z, c4.w};
        #pragma unroll
        for (int d = 0; d < 4; ++d) {
          float pv = (acc[kk][(m << 2) + d] - cv[d] * s0k[kk]) * 0.04f;
          acc[kk][(m << 2) + d] = pv;
          ss += pv * pv;
        }
      }
      ss += __shfl_xor(ss, 1); ss += __shfl_xor(ss, 2);
      rn[kk] = 1.f / fmaxf(sqrtf(ss), EPSN);
      if (cg == 0) gpart += ss * rn[kk] * rn[kk];
    }
    #pragma unroll
    for (int o = 1; o < 64; o <<= 1) gpart += __shfl_xor(gpart, o);
    const float gi = 1.f / fmaxf(sqrtf(gpart), EPSN);

    float* ob = out + (size_t)n * KCC * HWO + r;
    #pragma unroll
    for (int kk = 0; kk < 4; ++kk) {
      const int k = (kq << 2) + kk;
      #pragma unroll
      for (int j = 0; j < 32; ++j) {
        ob[(size_t)(k * CC + (cg << 5) + j) * HWO] = acc[kk][j] * rn[kk] * gi;
      }
    }
  } else {
    // ---------------- vlad_full partials: 25-pixel chunk ----------------
    const int pid = bid - 1296;            // 0..255
    const int n = pid >> 6, ch = pid & 63;
    const int pixb = n * HWP + ch * 25;    // global pixel index
    #pragma unroll
    for (int it = 0; it < 25; ++it) {
      a_s[it][lane] = aw[(size_t)(pixb + it) * KK_ + lane];
      const float* xp = xn + (size_t)(pixb + it) * CC;
      xs[it][swz(lane)]      = xp[lane];
      xs[it][swz(lane + 64)] = xp[lane + 64];
    }
    __syncthreads();
    float g0 = 0.f;
    #pragma unroll
    for (int p = 0; p < 25; ++p) g0 += a_s[p][lane];

    dots25(a_s, xs, kq, cg, acc);

    G0part[(size_t)pid * KK_ + lane] = g0;
    float* gb = Gpart + (size_t)pid * KCC + (cg << 5);
    #pragma unroll
    for (int kk = 0; kk < 4; ++kk) {
      const int k = (kq << 2) + kk;
      #pragma unroll
      for (int m = 0; m < 8; ++m) {
        float4 v;
        v.x = acc[kk][(m << 2) + 0]; v.y = acc[kk][(m << 2) + 1];
        v.z = acc[kk][(m << 2) + 2]; v.w = acc[kk][(m << 2) + 3];
        *(float4*)&gb[(size_t)k * CC + (m << 2)] = v;
      }
    }
  }
}

// =====================================================================
// Kernel 3: finalize vlad_full. 4 blocks (one per n) x 256 threads.
// =====================================================================
__global__ __launch_bounds__(256) void k3_full(
    const float* __restrict__ Gpart, const float* __restrict__ G0part,
    const float* __restrict__ cent, float* __restrict__ outF)
{
  __shared__ float red[4];
  const int n = blockIdx.x;
  const int t = threadIdx.x;
  const int k = t >> 2, cg = t & 3;

  float acc[32];
  #pragma unroll
  for (int j = 0; j < 32; ++j) acc[j] = 0.f;
  for (int ch = 0; ch < 64; ++ch) {
    const float* gp = Gpart + ((size_t)(n * 64 + ch)) * KCC + (size_t)k * CC + (cg << 5);
    #pragma unroll
    for (int m = 0; m < 8; ++m) {
      float4 g4 = *(const float4*)(gp + (m << 2));
      acc[(m << 2) + 0] += g4.x; acc[(m << 2) + 1] += g4.y;
      acc[(m << 2) + 2] += g4.z; acc[(m << 2) + 3] += g4.w;
    }
  }
  float g0 = 0.f;
  for (int ch = 0; ch < 64; ++ch) g0 += G0part[(size_t)(n * 64 + ch) * KK_ + k];

  float ss = 0.f;
  #pragma unroll
  for (int j = 0; j < 32; ++j) {
    const int c = (cg << 5) + j;
    float v = acc[j] - cent[(size_t)k * CC + c] * g0;
    acc[j] = v;
    ss += v * v;
  }
  ss += __shfl_xor(ss, 1); ss += __shfl_xor(ss, 2);
  const float rn = 1.f / fmaxf(sqrtf(ss), EPSN);
  float part = (cg == 0) ? ss * rn * rn : 0.f;
  #pragma unroll
  for (int o = 1; o < 64; o <<= 1) part += __shfl_xor(part, o);
  if ((t & 63) == 0) red[t >> 6] = part;
  __syncthreads();
  const float tot = red[0] + red[1] + red[2] + red[3];
  const float gi = 1.f / fmaxf(sqrtf(tot), EPSN);
  #pragma unroll
  for (int j = 0; j < 32; ++j)
    outF[(size_t)n * KCC + (size_t)k * CC + (cg << 5) + j] = acc[j] * rn * gi;
}

// =====================================================================
extern "C" void kernel_launch(void* const* d_in, const int* in_sizes, int n_in,
                              void* d_out, int out_size, void* d_ws, size_t ws_size,
                              hipStream_t stream)
{
  const float* x    = (const float*)d_in[0];
  const float* w    = (const float*)d_in[1];
  const float* cent = (const float*)d_in[2];
  float* out = (float*)d_out;
  float* ws  = (float*)d_ws;

  float* xn = ws + WS_XN;
  float* aw = ws + WS_A;
  float* gp = ws + WS_GP;
  float* g0 = ws + WS_G0;

  k1_norm_assign<<<dim3(100), dim3(512), 0, stream>>>(x, w, xn, aw);
  k2_main<<<dim3(1552), dim3(64), 0, stream>>>(xn, aw, cent, out, gp, g0);
  k3_full<<<dim3(NB), dim3(256), 0, stream>>>(gp, g0, cent,
                                              out + (size_t)NB * KCC * HWO);
}

// Round 3
// 156.889 us; speedup vs baseline: 1.4768x; 1.4768x over previous
//
#include <hip/hip_runtime.h>

#define EPSN 1e-12f

// ---- problem constants ----
#define NB   4
#define CC   128
#define KK_  64
#define HH   40
#define WW   40
#define HWP  1600      // H*W
#define HO   18
#define WO   18
#define HWO  324       // HO*WO
#define KCC  8192      // K*C

// ws layout (floats)
#define WS_XN  0                      // 4*1600*128 = 819200
#define WS_A   819200                 // 4*1600*64  = 409600
#define WS_GP  1228800                // 64*8192    = 524288
#define WS_G0  1753088                // 64*64      = 4096

// column swizzle for xs tiles: spread the 4 cg-phases (stride-32) across banks,
// preserving 4-float contiguity so b128 reads still work. Involution.
static __device__ __forceinline__ int swz(int c){ return c ^ ((c & 96) >> 3); }

// =====================================================================
// Kernel 1: per-pixel L2 norm -> xn (pix-major), conv dots + softmax -> a
// grid 100 x 1024 threads. 64 pixels per block. All global loads coalesced
// via LDS transpose.
// =====================================================================
__global__ __launch_bounds__(1024) void k1_norm_assign(
    const float* __restrict__ x, const float* __restrict__ w,
    float* __restrict__ xn, float* __restrict__ aout)
{
  __shared__ float xs[64][133];
  __shared__ float ds[64][65];
  __shared__ float invs[64];
  const int t = threadIdx.x;
  const int b = blockIdx.x;          // 0..99
  const int n = b / 25;
  const int pixb = (b % 25) * 64;
  const float* xb = x + (size_t)n * CC * HWP + pixb;

  // ---- Phase A: coalesced load + LDS transpose
  {
    const int pix = t & 63, cs = t >> 6;   // cs 0..15
    #pragma unroll
    for (int j = 0; j < 8; ++j) {
      const int c = cs + 16 * j;
      xs[pix][c] = xb[c * HWP + pix];      // 256B coalesced per instr
    }
  }
  __syncthreads();
  // ---- per-pixel sumsq -> inv norm
  {
    const int p = t >> 4, q = t & 15;
    float ss = 0.f;
    #pragma unroll
    for (int j = 0; j < 8; ++j) { float v = xs[p][q + 16 * j]; ss += v * v; }
    ss += __shfl_xor(ss, 1); ss += __shfl_xor(ss, 2);
    ss += __shfl_xor(ss, 4); ss += __shfl_xor(ss, 8);
    if (q == 0) invs[p] = 1.f / fmaxf(sqrtf(ss), EPSN);
  }
  __syncthreads();
  // ---- rescale in LDS + coalesced xn write
  {
    float* xno = xn + ((size_t)n * HWP + pixb) * CC;
    #pragma unroll
    for (int rr = 0; rr < 8; ++rr) {
      const int i = t + rr * 1024;
      const int pp = i >> 7, c = i & 127;
      const float v = xs[pp][c] * invs[pp];
      xs[pp][c] = v;
      xno[i] = v;
    }
  }
  __syncthreads();
  // ---- Phase B: dots. wave wv -> k = wv*4..wv*4+3 (wave-uniform w), lane=pixel
  {
    const int lane = t & 63;
    const int wv = __builtin_amdgcn_readfirstlane(t >> 6);   // 0..15
    float acc[4] = {0.f, 0.f, 0.f, 0.f};
    for (int c = 0; c < CC; ++c) {
      const float vn = xs[lane][c];
      #pragma unroll
      for (int kk = 0; kk < 4; ++kk)
        acc[kk] += vn * w[(wv * 4 + kk) * CC + c];
    }
    #pragma unroll
    for (int kk = 0; kk < 4; ++kk) ds[lane][wv * 4 + kk] = acc[kk];
  }
  __syncthreads();
  // ---- Phase C: softmax per pixel. thread (p = t>>4, q = t&15), k = q+16kk
  {
    const int p = t >> 4, q = t & 15;
    float v[4]; float m = -3.4e38f;
    #pragma unroll
    for (int kk = 0; kk < 4; ++kk){ v[kk] = ds[p][q + 16 * kk]; m = fmaxf(m, v[kk]); }
    m = fmaxf(m, __shfl_xor(m, 1)); m = fmaxf(m, __shfl_xor(m, 2));
    m = fmaxf(m, __shfl_xor(m, 4)); m = fmaxf(m, __shfl_xor(m, 8));
    float s = 0.f;
    #pragma unroll
    for (int kk = 0; kk < 4; ++kk){ v[kk] = __expf(v[kk] - m); s += v[kk]; }
    s += __shfl_xor(s, 1); s += __shfl_xor(s, 2);
    s += __shfl_xor(s, 4); s += __shfl_xor(s, 8);
    const float is = 1.f / s;
    #pragma unroll
    for (int kk = 0; kk < 4; ++kk) ds[p][q + 16 * kk] = v[kk] * is;
  }
  __syncthreads();
  {
    float* ao = aout + ((size_t)n * HWP + pixb) * KK_;
    #pragma unroll
    for (int rr = 0; rr < 4; ++rr) {
      const int i = t + rr * 1024;
      ao[i] = ds[i >> 6][i & 63];
    }
  }
}

// =====================================================================
// rank-25 outer-product accumulate: acc[c] += a[k]*xn[c]; also s0 += a[k].
// lane holds ONE k (k = wv*16 + (lane>>2)) and 32 c's (cg = lane&3).
// xs reads: 16-lane broadcast, swizzled -> conflict-free. a reads: 16 banks.
// =====================================================================
__device__ __forceinline__ void dots25(const float (*a_s)[64], const float (*xs)[128],
                                       int k, int cg, float acc[32], float& s0)
{
  #pragma unroll
  for (int p = 0; p < 25; ++p) {
    const float av = a_s[p][k];
    s0 += av;
    #pragma unroll
    for (int m = 0; m < 8; ++m) {
      const float4 x4 = *(const float4*)&xs[p][(cg << 5) + ((m ^ cg) << 2)];
      acc[(m << 2) + 0] += av * x4.x;
      acc[(m << 2) + 1] += av * x4.y;
      acc[(m << 2) + 2] += av * x4.z;
      acc[(m << 2) + 3] += av * x4.w;
    }
  }
}

// =====================================================================
// Kernel 2: 1296 regional-window blocks (write final vlad) + 64 blocks of
// vlad_full partials (100 pixels each). 256 threads (4 waves); K split
// across waves: wave wv owns k = wv*16 .. wv*16+15.
// =====================================================================
__global__ __launch_bounds__(256) void k2_main(
    const float* __restrict__ xn, const float* __restrict__ aw,
    const float* __restrict__ cent, float* __restrict__ out,
    float* __restrict__ Gpart, float* __restrict__ G0part)
{
  __shared__ __align__(16) float a_s[25][64];
  __shared__ __align__(16) float xs[25][128];
  __shared__ float red[4];
  const int t = threadIdx.x;
  const int lane = t & 63;
  const int wv = t >> 6;            // 0..3
  const int kq = lane >> 2;         // 0..15
  const int cg = lane & 3;          // 0..3
  const int k = wv * 16 + kq;
  // XCD-chunked bijective swizzle (1360 % 8 == 0): keeps hw-adjacent windows
  // on one XCD so the scattered 4B output stores merge in L2.
  const int bid = (blockIdx.x & 7) * 170 + (blockIdx.x >> 3);

  float acc[32];
  #pragma unroll
  for (int j = 0; j < 32; ++j) acc[j] = 0.f;
  float s0 = 0.f;

  if (bid < 1296) {
    // ---------------- regional window ----------------
    const int n = bid / HWO, r = bid % HWO, ho = r / WO, wo = r % WO;
    for (int it = wv; it < 25; it += 4) {
      const int pix = (2 * ho + it / 5) * WW + 2 * wo + (it % 5);
      a_s[it][lane] = aw[((size_t)n * HWP + pix) * KK_ + lane];
      const float* xp = xn + ((size_t)n * HWP + pix) * CC;
      xs[it][swz(lane)]      = xp[lane];
      xs[it][swz(lane + 64)] = xp[lane + 64];
    }
    __syncthreads();

    dots25(a_s, xs, k, cg, acc, s0);

    // epilogue: centroid correction, /25, intra-norm (C), global norm (K*C)
    float ss = 0.f;
    #pragma unroll
    for (int m = 0; m < 8; ++m) {
      const float4 c4 = *(const float4*)&cent[(size_t)k * CC + (cg << 5) + (m << 2)];
      const float cv[4] = {c4.x, c4.y, c4.z, c4.w};
      #pragma unroll
      for (int d = 0; d < 4; ++d) {
        const float pv = (acc[(m << 2) + d] - cv[d] * s0) * 0.04f;
        acc[(m << 2) + d] = pv;
        ss += pv * pv;
      }
    }
    ss += __shfl_xor(ss, 1); ss += __shfl_xor(ss, 2);   // over cg -> per-k sumsq
    const float rn = 1.f / fmaxf(sqrtf(ss), EPSN);
    float gp = (cg == 0) ? ss * rn * rn : 0.f;
    #pragma unroll
    for (int o = 1; o < 64; o <<= 1) gp += __shfl_xor(gp, o);
    if (lane == 0) red[wv] = gp;
    __syncthreads();
    const float gtot = red[0] + red[1] + red[2] + red[3];
    const float scale = rn * (1.f / fmaxf(sqrtf(gtot), EPSN));

    float* ob = out + (size_t)n * KCC * HWO + r;
    #pragma unroll
    for (int j = 0; j < 32; ++j)
      ob[(size_t)(k * CC + (cg << 5) + j) * HWO] = acc[j] * scale;
  } else {
    // ---------------- vlad_full partials: 100-pixel chunk, 4 rounds ------
    const int pid = bid - 1296;            // 0..63
    const int n = pid >> 4, ch = pid & 15;
    const int pixb = n * HWP + ch * 100;   // global pixel index
    #pragma unroll 1
    for (int rr = 0; rr < 4; ++rr) {
      for (int it = wv; it < 25; it += 4) {
        const int pg = pixb + rr * 25 + it;
        a_s[it][lane] = aw[(size_t)pg * KK_ + lane];
        const float* xp = xn + (size_t)pg * CC;
        xs[it][swz(lane)]      = xp[lane];
        xs[it][swz(lane + 64)] = xp[lane + 64];
      }
      __syncthreads();
      dots25(a_s, xs, k, cg, acc, s0);
      __syncthreads();
    }
    if (cg == 0) G0part[(size_t)pid * KK_ + k] = s0;
    float* gb = Gpart + (size_t)pid * KCC + (size_t)k * CC + (cg << 5);
    #pragma unroll
    for (int m = 0; m < 8; ++m) {
      float4 v;
      v.x = acc[(m << 2) + 0]; v.y = acc[(m << 2) + 1];
      v.z = acc[(m << 2) + 2]; v.w = acc[(m << 2) + 3];
      *(float4*)&gb[m << 2] = v;
    }
  }
}

// =====================================================================
// Kernel 3: finalize vlad_full. 4 blocks (one per n) x 1024 threads.
// thread: k = t>>4, 8 c's (c0 = (t&15)*8). Reads 2 MB coalesced.
// =====================================================================
__global__ __launch_bounds__(1024) void k3_full(
    const float* __restrict__ Gpart, const float* __restrict__ G0part,
    const float* __restrict__ cent, float* __restrict__ outF)
{
  __shared__ float red[16];
  const int n = blockIdx.x;
  const int t = threadIdx.x;
  const int k = t >> 4, cg16 = t & 15;
  const int c0 = cg16 * 8;

  float acc[8];
  #pragma unroll
  for (int j = 0; j < 8; ++j) acc[j] = 0.f;
  float g0 = 0.f;
  #pragma unroll 1
  for (int ch = 0; ch < 16; ++ch) {
    const float* gp = Gpart + ((size_t)(n * 16 + ch)) * KCC + (size_t)k * CC + c0;
    const float4 a4 = *(const float4*)(gp);
    const float4 b4 = *(const float4*)(gp + 4);
    acc[0] += a4.x; acc[1] += a4.y; acc[2] += a4.z; acc[3] += a4.w;
    acc[4] += b4.x; acc[5] += b4.y; acc[6] += b4.z; acc[7] += b4.w;
    g0 += G0part[(size_t)(n * 16 + ch) * KK_ + k];
  }

  float ss = 0.f;
  #pragma unroll
  for (int j = 0; j < 8; ++j) {
    const float v = acc[j] - cent[(size_t)k * CC + c0 + j] * g0;
    acc[j] = v;
    ss += v * v;
  }
  ss += __shfl_xor(ss, 1); ss += __shfl_xor(ss, 2);
  ss += __shfl_xor(ss, 4); ss += __shfl_xor(ss, 8);   // over cg16 -> per-k sumsq
  const float rn = 1.f / fmaxf(sqrtf(ss), EPSN);
  float part = (cg16 == 0) ? ss * rn * rn : 0.f;
  #pragma unroll
  for (int o = 1; o < 64; o <<= 1) part += __shfl_xor(part, o);
  if ((t & 63) == 0) red[t >> 6] = part;
  __syncthreads();
  float tot = 0.f;
  #pragma unroll
  for (int i = 0; i < 16; ++i) tot += red[i];
  const float scale = rn * (1.f / fmaxf(sqrtf(tot), EPSN));
  #pragma unroll
  for (int j = 0; j < 8; ++j)
    outF[(size_t)n * KCC + (size_t)k * CC + c0 + j] = acc[j] * scale;
}

// =====================================================================
extern "C" void kernel_launch(void* const* d_in, const int* in_sizes, int n_in,
                              void* d_out, int out_size, void* d_ws, size_t ws_size,
                              hipStream_t stream)
{
  const float* x    = (const float*)d_in[0];
  const float* w    = (const float*)d_in[1];
  const float* cent = (const float*)d_in[2];
  float* out = (float*)d_out;
  float* ws  = (float*)d_ws;

  float* xn = ws + WS_XN;
  float* aw = ws + WS_A;
  float* gp = ws + WS_GP;
  float* g0 = ws + WS_G0;

  k1_norm_assign<<<dim3(100), dim3(1024), 0, stream>>>(x, w, xn, aw);
  k2_main<<<dim3(1360), dim3(256), 0, stream>>>(xn, aw, cent, out, gp, g0);
  k3_full<<<dim3(NB), dim3(1024), 0, stream>>>(gp, g0, cent,
                                               out + (size_t)NB * KCC * HWO);
}